// Round 9
// baseline (187.746 us; speedup 1.0000x reference)
//
#include <hip/hip_runtime.h>

#define PI2_64 0.098174770424681038f   // 2*pi/64

// Sizes fixed: B=2, CI=CO=32, N=64, M=8.
// Freq map: t in [0,16): f = t (t<8) else t-16.
// Forward twiddle e^{-i*2pi*m/64}; inverse e^{+i*2pi*m/64}.

// ---- compile-time twiddle table: TW.c[m]=cos(2pi m/64), TW.s[m]=sin(2pi m/64)
constexpr float CQ17[17] = {
  1.0f,
  0.99518472667219693f, 0.98078528040323044f, 0.95694033573220886f,
  0.92387953251128674f, 0.88192126434835505f, 0.83146961230254524f,
  0.77301045336273699f, 0.70710678118654752f, 0.63439328416364549f,
  0.55557023301960222f, 0.47139673682599764f, 0.38268343236508977f,
  0.29028467725446236f, 0.19509032201612827f, 0.09801714032956060f,
  0.0f};
constexpr float ctw(int m0) {
  int m = ((m0 % 64) + 64) % 64;
  int n = (m > 32) ? (64 - m) : m;                 // cos(2pi(64-m)/64)=cos
  return (n <= 16) ? CQ17[n] : -CQ17[32 - n];      // cos(pi - x) = -cos(x)
}
struct Tw { float c[64]; float s[64]; };
constexpr Tw mkTw() {
  Tw t{};
  for (int m = 0; m < 64; ++m) { t.c[m] = ctw(m); t.s[m] = ctw(m - 16); }
  return t;
}
constexpr Tw TW = mkTw();

// ---- const-twiddle z-DFT: Z[k] += sum_i x[i] e^{-i 2pi k(16ZQ+i)/64} ----
template<int ZQ>
__device__ inline void zdft16(const float* xr, float* Zr, float* Zi) {
#pragma unroll
  for (int i = 0; i < 16; ++i) {
#pragma unroll
    for (int k = 0; k < 8; ++k) {
      const int m = (k * (ZQ * 16 + i)) & 63;
      Zr[k] = fmaf(xr[i], TW.c[m], Zr[k]);
      Zi[k] = fmaf(xr[i], -TW.s[m], Zi[k]);
    }
  }
}

// ---- const-twiddle z-expand: acc[i] += Re{ Y[v] e^{+i 2pi v(16ZQ+i)/64} } ----
template<int ZQ>
__device__ inline void zexp16(const float* Yr, const float* Yi, float* acc) {
#pragma unroll
  for (int v = 0; v < 8; ++v) {
#pragma unroll
    for (int i = 0; i < 16; ++i) {
      const int m = (v * (ZQ * 16 + i)) & 63;
      acc[i] = fmaf(Yr[v], TW.c[m], fmaf(Yi[v], -TW.s[m], acc[i]));
    }
  }
}

// ============ kA: fused forward z-DFT (64->8) + y-DFT (64->16) ==============
// grid 4096 = (b*32+ci)*64 + x ; block 256.
// Phase1: lane=(y 64, zq 4): 16 z in regs, const-twiddle FMA block, shfl.
// Phase2: lane=(jp 8, kz 8, h 4): E/O inline + +-freq trick, rot twiddles.
__global__ __launch_bounds__(256) void k_fwd_zy(const float* __restrict__ x,
                                                float* __restrict__ z2) {
  __shared__ __align__(16) float sp[64 * 68];     // plane [y][z], pad 68
  __shared__ __align__(8) float2 Zs[64 * 9];      // [y][kz], pad 9
  int tid = threadIdx.x;

  const float4* xg = (const float4*)(x + (long)blockIdx.x * 4096);
#pragma unroll
  for (int r = 0; r < 4; ++r) {
    int q = tid + 256 * r;
    float4 v = xg[q];
    int fl = q << 2;
    int y = fl >> 6, z = fl & 63;
    float* d = &sp[y * 68 + z];
    d[0] = v.x; d[1] = v.y; d[2] = v.z; d[3] = v.w;
  }
  __syncthreads();

  // ---- phase 1: z-DFT, Z[y][k] = sum_z x*e^{-i 2pi z k/64} ----
  {
    int y = tid >> 2, zq = tid & 3;
    const float4* row = (const float4*)(&sp[y * 68 + zq * 16]);
    float4 a0 = row[0], a1 = row[1], a2 = row[2], a3 = row[3];
    float xr[16] = {a0.x,a0.y,a0.z,a0.w, a1.x,a1.y,a1.z,a1.w,
                    a2.x,a2.y,a2.z,a2.w, a3.x,a3.y,a3.z,a3.w};
    float Zr[8] = {0,0,0,0,0,0,0,0}, Zi[8] = {0,0,0,0,0,0,0,0};
    switch (zq) {
      case 0: zdft16<0>(xr, Zr, Zi); break;
      case 1: zdft16<1>(xr, Zr, Zi); break;
      case 2: zdft16<2>(xr, Zr, Zi); break;
      default: zdft16<3>(xr, Zr, Zi); break;
    }
#pragma unroll
    for (int k = 0; k < 8; ++k) {
      Zr[k] += __shfl_xor(Zr[k], 1); Zr[k] += __shfl_xor(Zr[k], 2);
      Zi[k] += __shfl_xor(Zi[k], 1); Zi[k] += __shfl_xor(Zi[k], 2);
    }
    if (zq == 0) {
#pragma unroll
      for (int k = 0; k < 8; ++k) Zs[y * 9 + k] = make_float2(Zr[k], Zi[k]);
    }
  }
  __syncthreads();

  // ---- phase 2: y-DFT with E/O + +-j trick ----
  {
    int jp = tid >> 5, kz = (tid >> 2) & 7, h = tid & 3;
    int j = jp + 1;
    float S1 = 0, S2 = 0, S3 = 0, S4 = 0, S0r = 0, S0i = 0;
    int p0 = 8 * h + 1, pend = (h == 3) ? 32 : (p0 + 8);
    float c, s, stc, sts;
    __sincosf(PI2_64 * (float)((j * p0) & 63), &s, &c);
    __sincosf(PI2_64 * (float)j, &sts, &stc);
    for (int p = p0; p < pend; ++p) {
      float2 za = Zs[p * 9 + kz], zb = Zs[(64 - p) * 9 + kz];
      float Ex = za.x + zb.x, Ey = za.y + zb.y;
      float Ox = za.x - zb.x, Oy = za.y - zb.y;
      S1 = fmaf(Ex, c, S1); S2 = fmaf(Oy, s, S2);
      S3 = fmaf(Ey, c, S3); S4 = fmaf(Ox, s, S4);
      if (jp == 7) { S0r += Ex; S0i += Ey; }
      float nc = c * stc - s * sts; s = c * sts + s * stc; c = nc;
    }
    if (h == 3) {
      float2 z0 = Zs[kz], z32 = Zs[32 * 9 + kz];
      float sg = (j & 1) ? -1.f : 1.f;
      S1 += z0.x + sg * z32.x; S3 += z0.y + sg * z32.y;
      if (jp == 7) { S0r += z0.x + z32.x; S0i += z0.y + z32.y; }
    }
    S1 += __shfl_xor(S1, 1); S1 += __shfl_xor(S1, 2);
    S2 += __shfl_xor(S2, 1); S2 += __shfl_xor(S2, 2);
    S3 += __shfl_xor(S3, 1); S3 += __shfl_xor(S3, 2);
    S4 += __shfl_xor(S4, 1); S4 += __shfl_xor(S4, 2);
    S0r += __shfl_xor(S0r, 1); S0r += __shfl_xor(S0r, 2);
    S0i += __shfl_xor(S0i, 1); S0i += __shfl_xor(S0i, 2);
    if (h == 0) {
      float2* gz = (float2*)z2 + (long)blockIdx.x * 128;
      float2 vA = (jp < 7) ? make_float2(S1 + S2, S3 - S4) : make_float2(S0r, S0i);
      int tA = (jp < 7) ? j : 0;
      gz[tA * 8 + kz] = vA;
      gz[(16 - j) * 8 + kz] = make_float2(S1 - S2, S3 + S4);
    }
  }
}

// ============ A3: x-transform (64 x -> 16 t), REAL only, +-freq trick =======
// grid 1024 (= B*CI*16 u), block 128 = (jp 8, v 8, h 2).
__global__ __launch_bounds__(128) void k_fwd_x(const float* __restrict__ z2,
                                               float* __restrict__ xc) {
  __shared__ __align__(16) float2 Zs[64 * 10];    // [x][v], pad 10
  int tid = threadIdx.x;
  int bi = blockIdx.x >> 4;
  int u = blockIdx.x & 15;
  const float4* src = (const float4*)(z2 + (long)bi * 16384 + u * 16);
#pragma unroll
  for (int r = 0; r < 2; ++r) {
    int q = tid + 128 * r;
    int xx = q >> 2, pt = q & 3;
    float4 v = src[xx * 64 + pt];
    *(float4*)((float*)Zs + xx * 20 + pt * 4) = v;
  }
  __syncthreads();
  int jp = tid >> 4, v = (tid >> 1) & 7, h = tid & 1;
  int j = jp + 1;
  float S1 = 0, S2 = 0, S0 = 0;
  int p0 = 16 * h + 1, pend = (h == 1) ? 32 : 17;
  float c, s, stc, sts;
  __sincosf(PI2_64 * (float)((j * p0) & 63), &s, &c);
  __sincosf(PI2_64 * (float)j, &sts, &stc);
  for (int p = p0; p < pend; ++p) {
    float2 za = Zs[p * 10 + v], zb = Zs[(64 - p) * 10 + v];
    float Ex = za.x + zb.x, Oy = za.y - zb.y;
    S1 = fmaf(Ex, c, S1); S2 = fmaf(Oy, s, S2);
    if (jp == 7) S0 += Ex;
    float nc = c * stc - s * sts; s = c * sts + s * stc; c = nc;
  }
  if (h == 1) {
    float2 z0 = Zs[v], z32 = Zs[32 * 10 + v];
    float sg = (j & 1) ? -1.f : 1.f;
    S1 += z0.x + sg * z32.x;
    if (jp == 7) S0 += z0.x + z32.x;
  }
  S1 += __shfl_xor(S1, 1);
  S2 += __shfl_xor(S2, 1);
  S0 += __shfl_xor(S0, 1);
  if (h == 0) {
    float* xb = xc + (long)bi * 2048 + u * 8 + v;
    if (jp < 7) xb[j * 128] = S1 + S2; else xb[0] = S0;  // t=j / t=0
    xb[(16 - j) * 128] = S1 - S2;                        // t=16-j
  }
}

// ============ B: channel mix, u-paired for full-line weight reads ===========
// grid 256 = (b 2)*(t 16)*(uh 8), block 256 = (o 32)*(v 8); u = 2*uh, 2*uh+1
__global__ __launch_bounds__(256) void k_mix(const float* __restrict__ xc,
    const float* __restrict__ w1r, const float* __restrict__ w1i,
    const float* __restrict__ w2r, const float* __restrict__ w2i,
    const float* __restrict__ w3r, const float* __restrict__ w3i,
    const float* __restrict__ w4r, const float* __restrict__ w4i,
    float* __restrict__ outm) {
  __shared__ float sx[2 * 256];
  int tid = threadIdx.x;
  int b = blockIdx.x >> 7;
  int t = (blockIdx.x >> 3) & 15;
  int uh = blockIdx.x & 7;
  int u0 = uh * 2;
  {
    int i = tid >> 3, v = tid & 7;
    long base = (long)(b * 32 + i) * 2048 + t * 128;
    sx[tid]       = xc[base + u0 * 8 + v];
    sx[256 + tid] = xc[base + (u0 + 1) * 8 + v];
  }
  __syncthreads();
  const float* wr_ = (t < 8) ? ((u0 < 8) ? w1r : w3r) : ((u0 < 8) ? w2r : w4r);
  const float* wi_ = (t < 8) ? ((u0 < 8) ? w1i : w3i) : ((u0 < 8) ? w2i : w4i);
  int tm = t & 7, um0 = u0 & 7;
  int o = tid >> 3, v = tid & 7;
  long woff = (long)o * 512 + tm * 64 + um0 * 8 + v;
  float ar0 = 0, ai0 = 0, ar1 = 0, ai1 = 0;
#pragma unroll 4
  for (int i = 0; i < 32; ++i) {
    float x0 = sx[i * 8 + v], x1 = sx[256 + i * 8 + v];
    long wo = woff + (long)i * 16384;
    ar0 = fmaf(x0, wr_[wo], ar0);
    ai0 = fmaf(x0, wi_[wo], ai0);
    ar1 = fmaf(x1, wr_[wo + 8], ar1);
    ai1 = fmaf(x1, wi_[wo + 8], ai1);
  }
  long oi = (long)(b * 32 + o) * 2048 + t * 128 + u0 * 8 + v;
  ((float2*)outm)[oi] = make_float2(ar0, ai0);
  ((float2*)outm)[oi + 8] = make_float2(ar1, ai1);
}

// ============ kC: fused inverse x+y+z with +-freq pairing ===================
// grid 4096 = bo*64 + x ; block 256.
__global__ __launch_bounds__(256) void k_inv_xyz(const float* __restrict__ outm,
                                                 float* __restrict__ out) {
  __shared__ __align__(8) float2 E1[9 * 128], O1[9 * 128];  // [j][u*8+v]
  __shared__ __align__(16) float2 Y1c[128];                 // [u][v]
  __shared__ __align__(16) float2 Y2c[64 * 10];             // [y][v pad10]
  __shared__ __align__(8) float2 cs[64];
  __shared__ float rc[64], rs[64];
  int tid = threadIdx.x;
  int bo = blockIdx.x >> 6, xx = blockIdx.x & 63;

  if (tid < 64) {
    float s, c; __sincosf(PI2_64 * (float)tid, &s, &c);
    cs[tid] = make_float2(c, s); rc[tid] = c; rs[tid] = s;
  }
  // prepass: E/O over x-freq pairs, straight from global (L2-hot)
  const float2* pg = (const float2*)outm + (long)bo * 2048;
  for (int it = 0; it < 5; ++it) {
    int idx = tid + it * 256;
    if (idx < 1152) {
      int j = idx >> 7, uv = idx & 127;
      float2 pA = pg[j * 128 + uv];
      float2 E, O;
      if (j == 0)      { E = pA; O = make_float2(0.f, 0.f); }
      else if (j == 8) { E = pA; O = make_float2(-pA.x, -pA.y); }
      else {
        float2 pB = pg[(16 - j) * 128 + uv];
        E = make_float2(pA.x + pB.x, pA.y + pB.y);
        O = make_float2(pA.x - pB.x, pA.y - pB.y);
      }
      E1[idx] = E; O1[idx] = O;
    }
  }
  __syncthreads();

  // C1: x-expand at this xx. contribution: (Er*c - Oi*s, Ei*c + Or*s)
  {
    int u = tid >> 4, v = (tid >> 1) & 7, h = tid & 1;
    int uv = u * 8 + v;
    float Yr = 0, Yi = 0;
    int j0 = h ? 5 : 0, j1 = h ? 9 : 5;
    for (int j = j0; j < j1; ++j) {
      float2 E = E1[(j << 7) + uv], O = O1[(j << 7) + uv];
      float2 t = cs[(j * xx) & 63];          // uniform per block: broadcast
      Yr += E.x * t.x - O.y * t.y;
      Yi += E.y * t.x + O.x * t.y;
    }
    Yr += __shfl_xor(Yr, 1); Yi += __shfl_xor(Yi, 1);
    if (h == 0) Y1c[uv] = make_float2(Yr, Yi);
  }
  __syncthreads();

  // C2: y-expand, E/O on the fly (broadcast reads), 1/64^3 folded in
  {
    int y = tid & 63, vq = tid >> 6, v0 = vq * 2;
    float4 A0 = *(const float4*)(&Y1c[v0]);      // j=0 (u=0)
    float Yr0 = A0.x, Yi0 = A0.y, Yr1 = A0.z, Yi1 = A0.w;
#pragma unroll
    for (int j = 1; j < 8; ++j) {
      float4 Aj = *(const float4*)(&Y1c[j * 8 + v0]);
      float4 Bj = *(const float4*)(&Y1c[(16 - j) * 8 + v0]);
      int m = (j * y) & 63;
      float c = rc[m], s = rs[m];
      float E0r = Aj.x + Bj.x, E0i = Aj.y + Bj.y;
      float O0r = Aj.x - Bj.x, O0i = Aj.y - Bj.y;
      float E1r = Aj.z + Bj.z, E1i = Aj.w + Bj.w;
      float O1r = Aj.z - Bj.z, O1i = Aj.w - Bj.w;
      Yr0 += E0r * c - O0i * s; Yi0 += E0i * c + O0r * s;
      Yr1 += E1r * c - O1i * s; Yi1 += E1i * c + O1r * s;
    }
    {  // j=8 (u=8, f=-8): E=A, O=-A
      float4 Aj = *(const float4*)(&Y1c[64 + v0]);
      int m = (y * 8) & 63;
      float c = rc[m], s = rs[m];
      Yr0 += Aj.x * c + Aj.y * s; Yi0 += Aj.y * c - Aj.x * s;
      Yr1 += Aj.z * c + Aj.w * s; Yi1 += Aj.w * c - Aj.z * s;
    }
    const float sc = 1.f / 262144.f;
    *(float4*)(&Y2c[y * 10 + v0]) =
        make_float4(Yr0 * sc, Yi0 * sc, Yr1 * sc, Yi1 * sc);
  }
  __syncthreads();

  // C3: z-expand + Re. thread=(zq 4, y 64): row in regs, const twiddles
  {
    int y = tid & 63, zq = tid >> 6;
    const float4* rowp = (const float4*)(&Y2c[y * 10]);
    float4 r0 = rowp[0], r1 = rowp[1], r2 = rowp[2], r3 = rowp[3];
    float Yr[8] = {r0.x, r0.z, r1.x, r1.z, r2.x, r2.z, r3.x, r3.z};
    float Yi[8] = {r0.y, r0.w, r1.y, r1.w, r2.y, r2.w, r3.y, r3.w};
    float acc[16];
#pragma unroll
    for (int i = 0; i < 16; ++i) acc[i] = 0.f;
    switch (zq) {
      case 0: zexp16<0>(Yr, Yi, acc); break;
      case 1: zexp16<1>(Yr, Yi, acc); break;
      case 2: zexp16<2>(Yr, Yi, acc); break;
      default: zexp16<3>(Yr, Yi, acc); break;
    }
    float* ob = out + (long)blockIdx.x * 4096 + y * 64 + zq * 16;
#pragma unroll
    for (int q = 0; q < 4; ++q)
      ((float4*)ob)[q] = make_float4(acc[q*4], acc[q*4+1], acc[q*4+2], acc[q*4+3]);
  }
}

extern "C" void kernel_launch(void* const* d_in, const int* in_sizes, int n_in,
                              void* d_out, int out_size, void* d_ws, size_t ws_size,
                              hipStream_t stream) {
  (void)in_sizes; (void)n_in; (void)out_size; (void)ws_size;
  const float* x   = (const float*)d_in[0];
  const float* w1r = (const float*)d_in[1];
  const float* w1i = (const float*)d_in[2];
  const float* w2r = (const float*)d_in[3];
  const float* w2i = (const float*)d_in[4];
  const float* w3r = (const float*)d_in[5];
  const float* w3i = (const float*)d_in[6];
  const float* w4r = (const float*)d_in[7];
  const float* w4i = (const float*)d_in[8];
  float* out = (float*)d_out;
  float* ws = (float*)d_ws;

  float* z2   = ws;                 // 1,048,576 floats
  float* xc   = ws + 1048576;       //   131,072 floats
  float* outm = ws + 1179648;       //   262,144 floats

  k_fwd_zy <<<dim3(4096), dim3(256), 0, stream>>>(x, z2);
  k_fwd_x  <<<dim3(1024), dim3(128), 0, stream>>>(z2, xc);
  k_mix    <<<dim3(256),  dim3(256), 0, stream>>>(xc, w1r, w1i, w2r, w2i,
                                                  w3r, w3i, w4r, w4i, outm);
  k_inv_xyz<<<dim3(4096), dim3(256), 0, stream>>>(outm, out);
}